// Round 23
// baseline (308.069 us; speedup 1.0000x reference)
//
#include <hip/hip_runtime.h>

#define DD 128
#define NB 8
#define KTOT 1152   // 1024 (agg: k = kk*8 + b) + 128 (self-loop h)

typedef unsigned int uint_t;
typedef __attribute__((ext_vector_type(8))) _Float16 half8v;
typedef __attribute__((ext_vector_type(2))) _Float16 half2v;
typedef __attribute__((ext_vector_type(4))) float f32x4;
typedef __attribute__((ext_vector_type(2))) int int2v;
typedef __attribute__((ext_vector_type(4))) uint_t uint4v;

static __device__ __forceinline__ void gld_lds16(const _Float16* g, _Float16* l)
{
  __builtin_amdgcn_global_load_lds(
      (const __attribute__((address_space(1))) void*)g,
      (__attribute__((address_space(3))) void*)l, 16, 0, 0);
}

static __device__ __forceinline__ half2v bc_h2(uint_t u)
{
  union { uint_t u; half2v h; } c; c.u = u; return c.h;
}

static __device__ __forceinline__ float fdot2(uint_t a, uint_t b, float acc)
{
#if __has_builtin(__builtin_amdgcn_fdot2)
  return __builtin_amdgcn_fdot2(bc_h2(a), bc_h2(b), acc, false);
#else
  half2v x = bc_h2(a), y = bc_h2(b);
  return acc + (float)x[0] * (float)y[0] + (float)x[1] * (float)y[1];
#endif
}

// ---------------------------------------------------------------------------
// WcA[layer][ks][feat][j] = W[feat][k=ks*32+j]   (A-fragment-coalesced layout)
//   k<1024 -> bases[b=k&7][kk=k>>3][feat]; else loop_w[k-1024][feat]
// ---------------------------------------------------------------------------
__global__ __launch_bounds__(256) void k_prep_w(
    const float* __restrict__ bases1, const float* __restrict__ loopw1,
    const float* __restrict__ bases2, const float* __restrict__ loopw2,
    _Float16* __restrict__ WcA)
{
  int i = blockIdx.x * 256 + threadIdx.x;          // 2*36*128*32
  if (i >= 2 * 36 * DD * 32) return;
  int layer = i / (36 * DD * 32);
  int rem   = i % (36 * DD * 32);
  int ks    = rem / (DD * 32);
  int rem2  = rem % (DD * 32);
  int feat  = rem2 / 32;
  int j     = rem2 % 32;
  int k     = ks * 32 + j;
  const float* basesL = layer ? bases2 : bases1;
  const float* loopwL = layer ? loopw2 : loopw1;
  float v;
  if (k < 1024) {
    int kk = k >> 3, b = k & 7;
    v = basesL[((size_t)b * DD + kk) * DD + feat];
  } else {
    v = loopwL[(size_t)(k - 1024) * DD + feat];
  }
  WcA[i] = (_Float16)v;
}

// cast h (fp32, ids indirection) -> fp16 [N][128]
__global__ __launch_bounds__(256) void k_cast(
    const float* __restrict__ h, const int* __restrict__ ids,
    _Float16* __restrict__ hf, int N)
{
  int i = blockIdx.x * 256 + threadIdx.x;
  if (i >= N * (DD / 8)) return;
  int n  = i / (DD / 8);
  int k8 = (i % (DD / 8)) * 8;
  int row = ids ? ids[n] : n;
  const float* hp = h + (size_t)row * DD + k8;
  float4 v0 = *(const float4*)hp;
  float4 v1 = *(const float4*)(hp + 4);
  union { _Float16 e[8]; uint4 q; } p;
  p.e[0]=(_Float16)v0.x; p.e[1]=(_Float16)v0.y; p.e[2]=(_Float16)v0.z; p.e[3]=(_Float16)v0.w;
  p.e[4]=(_Float16)v1.x; p.e[5]=(_Float16)v1.y; p.e[6]=(_Float16)v1.z; p.e[7]=(_Float16)v1.w;
  *(uint4*)&hf[(size_t)n * DD + k8] = p.q;
}

// ------------------------------- CSR by dst --------------------------------
__global__ __launch_bounds__(256) void k_zero(int* __restrict__ p, int n)
{
  int i = blockIdx.x * 256 + threadIdx.x;
  if (i < n) p[i] = 0;
}

// histogram AND capture each edge's within-segment slot (atomic's return)
__global__ __launch_bounds__(256) void k_hist(
    const int* __restrict__ dst, int* __restrict__ cnt,
    int* __restrict__ slotin, int E)
{
  int e = blockIdx.x * 256 + threadIdx.x;
  if (e < E) slotin[e] = atomicAdd(&cnt[dst[e]], 1);
}

__global__ __launch_bounds__(256) void k_bsum(
    const int* __restrict__ cnt, int* __restrict__ bsum, int N)
{
  __shared__ int s[256];
  int i = blockIdx.x * 256 + threadIdx.x;
  s[threadIdx.x] = (i < N) ? ((cnt[i] + 1) & ~1) : 0;   // padded counts
  __syncthreads();
  for (int off = 128; off > 0; off >>= 1) {
    if (threadIdx.x < off) s[threadIdx.x] += s[threadIdx.x + off];
    __syncthreads();
  }
  if (threadIdx.x == 0) bsum[blockIdx.x] = s[0];
}

// exclusive block offsets + grand total (sum of padded counts, always even)
__global__ __launch_bounds__(256) void k_scanb(
    const int* __restrict__ bsum, int* __restrict__ boff,
    int* __restrict__ tot, int nb)
{
  __shared__ int s[256];
  int t = threadIdx.x;
  int own = (t < nb) ? bsum[t] : 0;
  s[t] = own;
  __syncthreads();
  for (int off = 1; off < 256; off <<= 1) {
    int v = (t >= off) ? s[t - off] : 0;
    __syncthreads();
    s[t] += v;
    __syncthreads();
  }
  if (t < nb) boff[t] = s[t] - own;     // exclusive
  if (t == nb - 1) tot[0] = s[t];       // grand total (even)
}

// scan + row_start; ALSO zero the (at most one) pad slot's en4 per node.
__global__ __launch_bounds__(256) void k_scan3(
    const int* __restrict__ cnt, const int* __restrict__ boff,
    int* __restrict__ row_start, int4* __restrict__ en4, int N)
{
  __shared__ int s[256];
  int t = threadIdx.x;
  int i = blockIdx.x * 256 + t;
  int c = (i < N) ? cnt[i] : 0;
  int v = (c + 1) & ~1;                                 // padded count
  s[t] = v;
  __syncthreads();
  for (int off = 1; off < 256; off <<= 1) {
    int u = (t >= off) ? s[t - off] : 0;
    __syncthreads();
    s[t] += u;
    __syncthreads();
  }
  if (i < N) {
    int rs = boff[blockIdx.x] + s[t] - v;
    row_start[i] = rs;
    if (c & 1) en4[rs + c] = make_int4(0, 0, 0, 0);     // pad slot
  }
}

// ---------------------------------------------------------------------------
// Place: ATOMIC-FREE, ONE 16B scattered store per edge:
// en4[slot] = {src, etype, norm_bits, 0}.
// ---------------------------------------------------------------------------
__global__ __launch_bounds__(256) void k_place(
    const int* __restrict__ dst, const int* __restrict__ src,
    const int* __restrict__ etype, const float* __restrict__ norm,
    const int* __restrict__ row_start, const int* __restrict__ slotin,
    int4* __restrict__ en4, int E)
{
  int e = blockIdx.x * 256 + threadIdx.x;
  if (e < E) {
    int slot = row_start[dst[e]] + slotin[e];
    en4[slot] = make_int4(src[e], etype[e], __float_as_int(norm[e]), 0);
  }
}

// ---------------------------------------------------------------------------
// Payload, one thread per slot PAIR below the device-computed total:
// read en4 linearly, write psrc (8B) and pair-interleaved fp16 coefficients
// c[pair][b][parity] (32B per layer).  Slots >= total never written nor read.
// ---------------------------------------------------------------------------
__global__ __launch_bounds__(256) void k_payload_pair(
    const int4* __restrict__ en4, const int* __restrict__ tot,
    const float* __restrict__ wcomp1, const float* __restrict__ wcomp2,
    int* __restrict__ psrc,
    _Float16* __restrict__ c1, _Float16* __restrict__ c2, int npair)
{
  int i = blockIdx.x * 256 + threadIdx.x;
  if (i >= npair || 2 * i >= tot[0]) return;
  int4 a = en4[2 * i], b = en4[2 * i + 1];
  float n0 = __int_as_float(a.z), n1 = __int_as_float(b.z);
  *(int2*)&psrc[2 * i] = make_int2(a.x, b.x);
  const float* w10 = wcomp1 + a.y * NB;
  const float* w11 = wcomp1 + b.y * NB;
  const float* w20 = wcomp2 + a.y * NB;
  const float* w21 = wcomp2 + b.y * NB;

  union { _Float16 h[16]; uint4 q[2]; } p;
  #pragma unroll
  for (int bb = 0; bb < NB; bb++) {
    p.h[bb * 2]     = (_Float16)(w10[bb] * n0);
    p.h[bb * 2 + 1] = (_Float16)(w11[bb] * n1);
  }
  *(uint4*)&c1[(size_t)i * 16]     = p.q[0];
  *(uint4*)&c1[(size_t)i * 16 + 8] = p.q[1];
  #pragma unroll
  for (int bb = 0; bb < NB; bb++) {
    p.h[bb * 2]     = (_Float16)(w20[bb] * n0);
    p.h[bb * 2 + 1] = (_Float16)(w21[bb] * n1);
  }
  *(uint4*)&c2[(size_t)i * 16]     = p.q[0];
  *(uint4*)&c2[(size_t)i * 16 + 8] = p.q[1];
}

// ---------------------------------------------------------------------------
// Aggregation: one wave per dst node; edge-pair fdot2 loop, 4 pairs in
// flight; vectorized uniform loads.  NONTEMPORAL (ext-vector types): agg
// stores (write-once, no write-allocate) and cpair/psrc loads (read-once).
// ---------------------------------------------------------------------------
__global__ __launch_bounds__(256) void k_agg(
    const int* __restrict__ rowst, const int* __restrict__ cnt,
    const int* __restrict__ psrc, const _Float16* __restrict__ cpair,
    const _Float16* __restrict__ hf,
    _Float16* __restrict__ agg, int N)
{
  int v = blockIdx.x * 4 + (threadIdx.x >> 6);
  if (v >= N) return;
  int lane = threadIdx.x & 63;
  const uint_t* hf32 = (const uint_t*)hf;
  const int beg = rowst[v];                    // even by construction
  const int npairs = (cnt[v] + 1) >> 1;
  const uint4v* cp4 = (const uint4v*)cpair + (size_t)(beg >> 1) * 2;
  const int2v* ps2 = (const int2v*)(psrc + beg);

  union U8 { uint4v q[2]; uint_t c[8]; };
  float ax[NB] = {}, ay[NB] = {};
  int i = 0;
  for (; i + 4 <= npairs; i += 4) {
    int2v s01 = __builtin_nontemporal_load(ps2 + i);
    int2v s23 = __builtin_nontemporal_load(ps2 + i + 1);
    int2v s45 = __builtin_nontemporal_load(ps2 + i + 2);
    int2v s67 = __builtin_nontemporal_load(ps2 + i + 3);
    uint_t u0 = hf32[(size_t)s01.x * 64 + lane];
    uint_t u1 = hf32[(size_t)s01.y * 64 + lane];
    uint_t u2 = hf32[(size_t)s23.x * 64 + lane];
    uint_t u3 = hf32[(size_t)s23.y * 64 + lane];
    uint_t u4 = hf32[(size_t)s45.x * 64 + lane];
    uint_t u5 = hf32[(size_t)s45.y * 64 + lane];
    uint_t u6 = hf32[(size_t)s67.x * 64 + lane];
    uint_t u7 = hf32[(size_t)s67.y * 64 + lane];
    uint_t lo[4], hi[4];
    lo[0] = __builtin_amdgcn_perm(u0, u1, 0x01000504);
    hi[0] = __builtin_amdgcn_perm(u0, u1, 0x03020706);
    lo[1] = __builtin_amdgcn_perm(u2, u3, 0x01000504);
    hi[1] = __builtin_amdgcn_perm(u2, u3, 0x03020706);
    lo[2] = __builtin_amdgcn_perm(u4, u5, 0x01000504);
    hi[2] = __builtin_amdgcn_perm(u4, u5, 0x03020706);
    lo[3] = __builtin_amdgcn_perm(u6, u7, 0x01000504);
    hi[3] = __builtin_amdgcn_perm(u6, u7, 0x03020706);
    U8 C0, C1, C2, C3;
    C0.q[0] = __builtin_nontemporal_load(cp4 + 2*i + 0);
    C0.q[1] = __builtin_nontemporal_load(cp4 + 2*i + 1);
    C1.q[0] = __builtin_nontemporal_load(cp4 + 2*i + 2);
    C1.q[1] = __builtin_nontemporal_load(cp4 + 2*i + 3);
    C2.q[0] = __builtin_nontemporal_load(cp4 + 2*i + 4);
    C2.q[1] = __builtin_nontemporal_load(cp4 + 2*i + 5);
    C3.q[0] = __builtin_nontemporal_load(cp4 + 2*i + 6);
    C3.q[1] = __builtin_nontemporal_load(cp4 + 2*i + 7);
    #pragma unroll
    for (int b = 0; b < NB; b++) {
      ax[b] = fdot2(C0.c[b], lo[0], ax[b]); ay[b] = fdot2(C0.c[b], hi[0], ay[b]);
      ax[b] = fdot2(C1.c[b], lo[1], ax[b]); ay[b] = fdot2(C1.c[b], hi[1], ay[b]);
      ax[b] = fdot2(C2.c[b], lo[2], ax[b]); ay[b] = fdot2(C2.c[b], hi[2], ay[b]);
      ax[b] = fdot2(C3.c[b], lo[3], ax[b]); ay[b] = fdot2(C3.c[b], hi[3], ay[b]);
    }
  }
  for (; i < npairs; i++) {
    int2v s01 = __builtin_nontemporal_load(ps2 + i);
    uint_t u0 = hf32[(size_t)s01.x * 64 + lane];
    uint_t u1 = hf32[(size_t)s01.y * 64 + lane];
    uint_t lo0 = __builtin_amdgcn_perm(u0, u1, 0x01000504);
    uint_t hi0 = __builtin_amdgcn_perm(u0, u1, 0x03020706);
    U8 C0;
    C0.q[0] = __builtin_nontemporal_load(cp4 + 2*i + 0);
    C0.q[1] = __builtin_nontemporal_load(cp4 + 2*i + 1);
    #pragma unroll
    for (int b = 0; b < NB; b++) {
      ax[b] = fdot2(C0.c[b], lo0, ax[b]);
      ay[b] = fdot2(C0.c[b], hi0, ay[b]);
    }
  }

  union { _Float16 e[8]; uint4v q; } p0, p1;
  #pragma unroll
  for (int b = 0; b < NB; b++) { p0.e[b] = (_Float16)ax[b]; p1.e[b] = (_Float16)ay[b]; }
  uint4v* dstp = (uint4v*)&agg[(size_t)v * 1024 + lane * 16];
  __builtin_nontemporal_store(p0.q, dstp);
  __builtin_nontemporal_store(p1.q, dstp + 1);
}

// ---------------------------------------------------------------------------
// MFMA GEMM: TN=64, 512 threads / 8 waves, BK=128 (9 K-tiles: 8 agg + 1 hf).
// LDS tile: [16 kslot][64 node][8 halves] = 16KB, double-buffered.
// Wave wv stages kslots wv and wv+8 (2 gld_lds per tile, lane = node).
// COMPUTE: 4 sub-steps x {1 A-load (L2-hot WcA) + 4 ds_read + 4 MFMA}.
// ---------------------------------------------------------------------------
template <int LAYER>
__global__ __launch_bounds__(512) void k_mm(
    const _Float16* __restrict__ agg,   // [N][1024]
    const _Float16* __restrict__ hf,    // [N][128]
    const _Float16* __restrict__ WcA,   // [36][128][32]
    const float* __restrict__ bias,
    float* __restrict__ outf, _Float16* __restrict__ outh, int N)
{
  __shared__ _Float16 sB[2][8192];      // 2 x 16KB

  const int n0   = blockIdx.x * 64;
  const int wv   = threadIdx.x >> 6;    // 0..7
  const int lane = threadIdx.x & 63;
  const int l15  = lane & 15, l4 = lane >> 4;

  int nodeL = n0 + lane; if (nodeL >= N) nodeL = N - 1;   // stage-source clamp

  f32x4 acc[4];
  #pragma unroll
  for (int b = 0; b < 4; b++) acc[b] = (f32x4)0.f;

  const int fbase = wv * 16 + l15;
  const int koff  = l4 * 8;

  auto STAGE = [&](int buf, int t) {    // t in 0..8
    const _Float16* g;
    if (t < 8) g = &agg[(size_t)nodeL * 1024 + t * 128 + wv * 8];
    else       g = &hf [(size_t)nodeL * DD   + wv * 8];
    gld_lds16(g,      &sB[buf][ wv      * 512]);   // kslot wv
    gld_lds16(g + 64, &sB[buf][(wv + 8) * 512]);   // kslot wv+8
  };

  auto COMPUTE = [&](int buf, int t) {
    #pragma unroll
    for (int s = 0; s < 4; s++) {
      const int ks = 4 * t + s;         // 0..35
      half8v af = *(const half8v*)&WcA[((size_t)ks * DD + fbase) * 32 + koff];
      half8v bfr[4];
      #pragma unroll
      for (int nf = 0; nf < 4; nf++)
        bfr[nf] = *(const half8v*)&sB[buf][(s * 4 + l4) * 512 + (nf * 16 + l15) * 8];
      #pragma unroll
      for (int nf = 0; nf < 4; nf++)
        acc[nf] = __builtin_amdgcn_mfma_f32_16x16x32_f16(af, bfr[nf], acc[nf], 0, 0, 0);
    }
  };

  STAGE(0, 0);
  __syncthreads();
  int cur = 0;
  for (int t = 0; t < 8; t++) {
    STAGE(cur ^ 1, t + 1);
    COMPUTE(cur, t);
    __syncthreads();
    cur ^= 1;
  }
  COMPUTE(cur, 8);

  // C layout: col(=node) = lane&15, row(=feat) = l4*4 + r
  #pragma unroll
  for (int nf = 0; nf < 4; nf++) {
    int n = n0 + nf * 16 + l15;
    if (n >= N) continue;
    int feat = wv * 16 + l4 * 4;
    if (LAYER == 1) {
      union { _Float16 e[4]; uint2 q; } p;
      #pragma unroll
      for (int r = 0; r < 4; r++)
        p.e[r] = (_Float16)fmaxf(acc[nf][r] + bias[feat + r], 0.f);
      *(uint2*)&outh[(size_t)n * DD + feat] = p.q;
    } else {
      float4 o;
      o.x = acc[nf][0] + bias[feat + 0];
      o.y = acc[nf][1] + bias[feat + 1];
      o.z = acc[nf][2] + bias[feat + 2];
      o.w = acc[nf][3] + bias[feat + 3];
      *(float4*)&outf[(size_t)n * DD + feat] = o;
    }
  }
}

extern "C" void kernel_launch(void* const* d_in, const int* in_sizes, int n_in,
                              void* d_out, int out_size, void* d_ws, size_t ws_size,
                              hipStream_t stream)
{
  const int*   h_ids     = (const int*)d_in[0];
  const int*   src       = (const int*)d_in[1];
  const int*   dst       = (const int*)d_in[2];
  const int*   etype     = (const int*)d_in[3];
  const float* norm      = (const float*)d_in[4];
  const float* embedding = (const float*)d_in[5];
  const float* w_comp1   = (const float*)d_in[6];
  const float* bases1    = (const float*)d_in[7];
  const float* loop_w1   = (const float*)d_in[8];
  const float* bias1     = (const float*)d_in[9];
  const float* w_comp2   = (const float*)d_in[10];
  const float* bases2    = (const float*)d_in[11];
  const float* loop_w2   = (const float*)d_in[12];
  const float* bias2     = (const float*)d_in[13];

  const int N = in_sizes[0];
  const int E = in_sizes[1];
  const int S = (E + N) & ~1;           // padded-slot capacity (even)
  const int NPAIR = S >> 1;
  const int NBLK = (N + 255) / 256;     // <= 256 (N <= 65536)

  // ---- workspace carve-up (256B aligned) ----
  char* base = (char*)d_ws;
  size_t off = 0;
  auto alloc = [&](size_t bytes) -> char* {
    char* p = base + off;
    off += (bytes + 255) & ~(size_t)255;
    return p;
  };
  _Float16* agg  = (_Float16*)alloc((size_t)N * 1024 * 2);   // 102.4 MB
  _Float16* hfp  = (_Float16*)alloc((size_t)N * DD * 2);     // 12.8 MB
  _Float16* h1h  = (_Float16*)alloc((size_t)N * DD * 2);     // 12.8 MB
  _Float16* WcA  = (_Float16*)alloc((size_t)2 * 36 * DD * 32 * 2);
  int*      cnt    = (int*)   alloc((size_t)N * 4);
  int4*     en4    = (int4*)  alloc((size_t)S * 16);
  int*      rowst  = (int*)   alloc((size_t)N * 4);
  int*      bsum   = (int*)   alloc(256 * 4);
  int*      boff   = (int*)   alloc(256 * 4);
  int*      tot    = (int*)   alloc(256);
  int*      slotin = (int*)   alloc((size_t)E * 4);
  int*      psrc   = (int*)   alloc((size_t)S * 4);
  _Float16* c1     = (_Float16*)alloc((size_t)S * 8 * 2);    // ~10.4 MB
  _Float16* c2     = (_Float16*)alloc((size_t)S * 8 * 2);    // ~10.4 MB
  float*    out    = (float*)d_out;

  // ---- build padded CSR by dst (reused by both layers) ----
  k_zero <<<(N + 255) / 256, 256, 0, stream>>>(cnt, N);
  k_hist <<<(E + 255) / 256, 256, 0, stream>>>(dst, cnt, slotin, E);
  k_bsum <<<NBLK, 256, 0, stream>>>(cnt, bsum, N);
  k_scanb<<<1, 256, 0, stream>>>(bsum, boff, tot, NBLK);
  k_scan3<<<NBLK, 256, 0, stream>>>(cnt, boff, rowst, en4, N);
  k_place<<<(E + 255) / 256, 256, 0, stream>>>(dst, src, etype, norm,
                                               rowst, slotin, en4, E);
  k_payload_pair<<<(NPAIR + 255) / 256, 256, 0, stream>>>(
      en4, tot, w_comp1, w_comp2, psrc, c1, c2, NPAIR);

  // ---- weights -> fp16 A-coalesced layout ----
  k_prep_w<<<(2 * 36 * DD * 32 + 255) / 256, 256, 0, stream>>>(bases1, loop_w1, bases2, loop_w2, WcA);

  dim3 gmm((N + 63) / 64);
  int gagg = (N + 3) / 4;

  // ---- layer 1 ----
  k_cast<<<(N * (DD / 8) + 255) / 256, 256, 0, stream>>>(embedding, h_ids, hfp, N);
  k_agg<<<gagg, 256, 0, stream>>>(rowst, cnt, psrc, c1, hfp, agg, N);
  k_mm<1><<<gmm, 512, 0, stream>>>(agg, hfp, WcA, bias1, nullptr, h1h, N);

  // ---- layer 2 ----
  k_agg<<<gagg, 256, 0, stream>>>(rowst, cnt, psrc, c2, h1h, agg, N);
  k_mm<2><<<gmm, 512, 0, stream>>>(agg, h1h, WcA + (size_t)36 * DD * 32, bias2, out, nullptr, N);
}

// Round 24
// 244.008 us; speedup vs baseline: 1.2625x; 1.2625x over previous
//
#include <hip/hip_runtime.h>

#define DD 128
#define NB 8
#define KTOT 1152   // 1024 (agg: k = kk*8 + b) + 128 (self-loop h)

typedef unsigned int uint_t;
typedef __attribute__((ext_vector_type(8))) _Float16 half8v;
typedef __attribute__((ext_vector_type(2))) _Float16 half2v;
typedef __attribute__((ext_vector_type(4))) float f32x4;

static __device__ __forceinline__ void gld_lds16(const _Float16* g, _Float16* l)
{
  __builtin_amdgcn_global_load_lds(
      (const __attribute__((address_space(1))) void*)g,
      (__attribute__((address_space(3))) void*)l, 16, 0, 0);
}

static __device__ __forceinline__ half2v bc_h2(uint_t u)
{
  union { uint_t u; half2v h; } c; c.u = u; return c.h;
}

static __device__ __forceinline__ float fdot2(uint_t a, uint_t b, float acc)
{
#if __has_builtin(__builtin_amdgcn_fdot2)
  return __builtin_amdgcn_fdot2(bc_h2(a), bc_h2(b), acc, false);
#else
  half2v x = bc_h2(a), y = bc_h2(b);
  return acc + (float)x[0] * (float)y[0] + (float)x[1] * (float)y[1];
#endif
}

// ---------------------------------------------------------------------------
// WcA[layer][ks][feat][j] = W[feat][k=ks*32+j]   (A-fragment-coalesced layout)
//   k<1024 -> bases[b=k&7][kk=k>>3][feat]; else loop_w[k-1024][feat]
// ---------------------------------------------------------------------------
__global__ __launch_bounds__(256) void k_prep_w(
    const float* __restrict__ bases1, const float* __restrict__ loopw1,
    const float* __restrict__ bases2, const float* __restrict__ loopw2,
    _Float16* __restrict__ WcA)
{
  int i = blockIdx.x * 256 + threadIdx.x;          // 2*36*128*32
  if (i >= 2 * 36 * DD * 32) return;
  int layer = i / (36 * DD * 32);
  int rem   = i % (36 * DD * 32);
  int ks    = rem / (DD * 32);
  int rem2  = rem % (DD * 32);
  int feat  = rem2 / 32;
  int j     = rem2 % 32;
  int k     = ks * 32 + j;
  const float* basesL = layer ? bases2 : bases1;
  const float* loopwL = layer ? loopw2 : loopw1;
  float v;
  if (k < 1024) {
    int kk = k >> 3, b = k & 7;
    v = basesL[((size_t)b * DD + kk) * DD + feat];
  } else {
    v = loopwL[(size_t)(k - 1024) * DD + feat];
  }
  WcA[i] = (_Float16)v;
}

// cast h (fp32, ids indirection) -> fp16 [N][128]
__global__ __launch_bounds__(256) void k_cast(
    const float* __restrict__ h, const int* __restrict__ ids,
    _Float16* __restrict__ hf, int N)
{
  int i = blockIdx.x * 256 + threadIdx.x;
  if (i >= N * (DD / 8)) return;
  int n  = i / (DD / 8);
  int k8 = (i % (DD / 8)) * 8;
  int row = ids ? ids[n] : n;
  const float* hp = h + (size_t)row * DD + k8;
  float4 v0 = *(const float4*)hp;
  float4 v1 = *(const float4*)(hp + 4);
  union { _Float16 e[8]; uint4 q; } p;
  p.e[0]=(_Float16)v0.x; p.e[1]=(_Float16)v0.y; p.e[2]=(_Float16)v0.z; p.e[3]=(_Float16)v0.w;
  p.e[4]=(_Float16)v1.x; p.e[5]=(_Float16)v1.y; p.e[6]=(_Float16)v1.z; p.e[7]=(_Float16)v1.w;
  *(uint4*)&hf[(size_t)n * DD + k8] = p.q;
}

// ------------------------------- CSR by dst --------------------------------
__global__ __launch_bounds__(256) void k_zero(int* __restrict__ p, int n)
{
  int i = blockIdx.x * 256 + threadIdx.x;
  if (i < n) p[i] = 0;
}

// histogram AND capture each edge's within-segment slot (atomic's return)
__global__ __launch_bounds__(256) void k_hist(
    const int* __restrict__ dst, int* __restrict__ cnt,
    int* __restrict__ slotin, int E)
{
  int e = blockIdx.x * 256 + threadIdx.x;
  if (e < E) slotin[e] = atomicAdd(&cnt[dst[e]], 1);
}

__global__ __launch_bounds__(256) void k_bsum(
    const int* __restrict__ cnt, int* __restrict__ bsum, int N)
{
  __shared__ int s[256];
  int i = blockIdx.x * 256 + threadIdx.x;
  s[threadIdx.x] = (i < N) ? ((cnt[i] + 1) & ~1) : 0;   // padded counts
  __syncthreads();
  for (int off = 128; off > 0; off >>= 1) {
    if (threadIdx.x < off) s[threadIdx.x] += s[threadIdx.x + off];
    __syncthreads();
  }
  if (threadIdx.x == 0) bsum[blockIdx.x] = s[0];
}

// exclusive block offsets + grand total (sum of padded counts, always even)
__global__ __launch_bounds__(256) void k_scanb(
    const int* __restrict__ bsum, int* __restrict__ boff,
    int* __restrict__ tot, int nb)
{
  __shared__ int s[256];
  int t = threadIdx.x;
  int own = (t < nb) ? bsum[t] : 0;
  s[t] = own;
  __syncthreads();
  for (int off = 1; off < 256; off <<= 1) {
    int v = (t >= off) ? s[t - off] : 0;
    __syncthreads();
    s[t] += v;
    __syncthreads();
  }
  if (t < nb) boff[t] = s[t] - own;     // exclusive
  if (t == nb - 1) tot[0] = s[t];       // grand total (even)
}

// scan + row_start; ALSO zero the (at most one) pad slot's en4 per node.
__global__ __launch_bounds__(256) void k_scan3(
    const int* __restrict__ cnt, const int* __restrict__ boff,
    int* __restrict__ row_start, int4* __restrict__ en4, int N)
{
  __shared__ int s[256];
  int t = threadIdx.x;
  int i = blockIdx.x * 256 + t;
  int c = (i < N) ? cnt[i] : 0;
  int v = (c + 1) & ~1;                                 // padded count
  s[t] = v;
  __syncthreads();
  for (int off = 1; off < 256; off <<= 1) {
    int u = (t >= off) ? s[t - off] : 0;
    __syncthreads();
    s[t] += u;
    __syncthreads();
  }
  if (i < N) {
    int rs = boff[blockIdx.x] + s[t] - v;
    row_start[i] = rs;
    if (c & 1) en4[rs + c] = make_int4(0, 0, 0, 0);     // pad slot
  }
}

// ---------------------------------------------------------------------------
// Place: ATOMIC-FREE, ONE 16B scattered store per edge:
// en4[slot] = {src, etype, norm_bits, 0}.
// ---------------------------------------------------------------------------
__global__ __launch_bounds__(256) void k_place(
    const int* __restrict__ dst, const int* __restrict__ src,
    const int* __restrict__ etype, const float* __restrict__ norm,
    const int* __restrict__ row_start, const int* __restrict__ slotin,
    int4* __restrict__ en4, int E)
{
  int e = blockIdx.x * 256 + threadIdx.x;
  if (e < E) {
    int slot = row_start[dst[e]] + slotin[e];
    en4[slot] = make_int4(src[e], etype[e], __float_as_int(norm[e]), 0);
  }
}

// ---------------------------------------------------------------------------
// Payload, one thread per slot PAIR below the device-computed total:
// read en4 linearly, write psrc (8B) and pair-interleaved fp16 coefficients
// c[pair][b][parity] (32B per layer).  Slots >= total never written nor read.
// ---------------------------------------------------------------------------
__global__ __launch_bounds__(256) void k_payload_pair(
    const int4* __restrict__ en4, const int* __restrict__ tot,
    const float* __restrict__ wcomp1, const float* __restrict__ wcomp2,
    int* __restrict__ psrc,
    _Float16* __restrict__ c1, _Float16* __restrict__ c2, int npair)
{
  int i = blockIdx.x * 256 + threadIdx.x;
  if (i >= npair || 2 * i >= tot[0]) return;
  int4 a = en4[2 * i], b = en4[2 * i + 1];
  float n0 = __int_as_float(a.z), n1 = __int_as_float(b.z);
  *(int2*)&psrc[2 * i] = make_int2(a.x, b.x);
  const float* w10 = wcomp1 + a.y * NB;
  const float* w11 = wcomp1 + b.y * NB;
  const float* w20 = wcomp2 + a.y * NB;
  const float* w21 = wcomp2 + b.y * NB;

  union { _Float16 h[16]; uint4 q[2]; } p;
  #pragma unroll
  for (int bb = 0; bb < NB; bb++) {
    p.h[bb * 2]     = (_Float16)(w10[bb] * n0);
    p.h[bb * 2 + 1] = (_Float16)(w11[bb] * n1);
  }
  *(uint4*)&c1[(size_t)i * 16]     = p.q[0];
  *(uint4*)&c1[(size_t)i * 16 + 8] = p.q[1];
  #pragma unroll
  for (int bb = 0; bb < NB; bb++) {
    p.h[bb * 2]     = (_Float16)(w20[bb] * n0);
    p.h[bb * 2 + 1] = (_Float16)(w21[bb] * n1);
  }
  *(uint4*)&c2[(size_t)i * 16]     = p.q[0];
  *(uint4*)&c2[(size_t)i * 16 + 8] = p.q[1];
}

// ---------------------------------------------------------------------------
// Aggregation: one wave per dst node; edge-pair fdot2 loop, 4 pairs in
// flight; vectorized uniform loads (uint4 coeffs, int2 psrc).
// ---------------------------------------------------------------------------
__global__ __launch_bounds__(256) void k_agg(
    const int* __restrict__ rowst, const int* __restrict__ cnt,
    const int* __restrict__ psrc, const _Float16* __restrict__ cpair,
    const _Float16* __restrict__ hf,
    _Float16* __restrict__ agg, int N)
{
  int v = blockIdx.x * 4 + (threadIdx.x >> 6);
  if (v >= N) return;
  int lane = threadIdx.x & 63;
  const uint_t* hf32 = (const uint_t*)hf;
  const int beg = rowst[v];                    // even by construction
  const int npairs = (cnt[v] + 1) >> 1;
  const uint4* cp4 = (const uint4*)cpair + (size_t)(beg >> 1) * 2;
  const int* ps = psrc + beg;

  union U8 { uint4 q[2]; uint_t c[8]; };
  float ax[NB] = {}, ay[NB] = {};
  int i = 0;
  for (; i + 4 <= npairs; i += 4) {
    int2 s01 = *(const int2*)(ps + 2*i);
    int2 s23 = *(const int2*)(ps + 2*i + 2);
    int2 s45 = *(const int2*)(ps + 2*i + 4);
    int2 s67 = *(const int2*)(ps + 2*i + 6);
    uint_t u0 = hf32[(size_t)s01.x * 64 + lane];
    uint_t u1 = hf32[(size_t)s01.y * 64 + lane];
    uint_t u2 = hf32[(size_t)s23.x * 64 + lane];
    uint_t u3 = hf32[(size_t)s23.y * 64 + lane];
    uint_t u4 = hf32[(size_t)s45.x * 64 + lane];
    uint_t u5 = hf32[(size_t)s45.y * 64 + lane];
    uint_t u6 = hf32[(size_t)s67.x * 64 + lane];
    uint_t u7 = hf32[(size_t)s67.y * 64 + lane];
    uint_t lo[4], hi[4];
    lo[0] = __builtin_amdgcn_perm(u0, u1, 0x01000504);
    hi[0] = __builtin_amdgcn_perm(u0, u1, 0x03020706);
    lo[1] = __builtin_amdgcn_perm(u2, u3, 0x01000504);
    hi[1] = __builtin_amdgcn_perm(u2, u3, 0x03020706);
    lo[2] = __builtin_amdgcn_perm(u4, u5, 0x01000504);
    hi[2] = __builtin_amdgcn_perm(u4, u5, 0x03020706);
    lo[3] = __builtin_amdgcn_perm(u6, u7, 0x01000504);
    hi[3] = __builtin_amdgcn_perm(u6, u7, 0x03020706);
    U8 C0, C1, C2, C3;
    C0.q[0] = cp4[2*i + 0]; C0.q[1] = cp4[2*i + 1];
    C1.q[0] = cp4[2*i + 2]; C1.q[1] = cp4[2*i + 3];
    C2.q[0] = cp4[2*i + 4]; C2.q[1] = cp4[2*i + 5];
    C3.q[0] = cp4[2*i + 6]; C3.q[1] = cp4[2*i + 7];
    #pragma unroll
    for (int b = 0; b < NB; b++) {
      ax[b] = fdot2(C0.c[b], lo[0], ax[b]); ay[b] = fdot2(C0.c[b], hi[0], ay[b]);
      ax[b] = fdot2(C1.c[b], lo[1], ax[b]); ay[b] = fdot2(C1.c[b], hi[1], ay[b]);
      ax[b] = fdot2(C2.c[b], lo[2], ax[b]); ay[b] = fdot2(C2.c[b], hi[2], ay[b]);
      ax[b] = fdot2(C3.c[b], lo[3], ax[b]); ay[b] = fdot2(C3.c[b], hi[3], ay[b]);
    }
  }
  for (; i < npairs; i++) {
    int2 s01 = *(const int2*)(ps + 2*i);
    uint_t u0 = hf32[(size_t)s01.x * 64 + lane];
    uint_t u1 = hf32[(size_t)s01.y * 64 + lane];
    uint_t lo0 = __builtin_amdgcn_perm(u0, u1, 0x01000504);
    uint_t hi0 = __builtin_amdgcn_perm(u0, u1, 0x03020706);
    U8 C0;
    C0.q[0] = cp4[2*i + 0]; C0.q[1] = cp4[2*i + 1];
    #pragma unroll
    for (int b = 0; b < NB; b++) {
      ax[b] = fdot2(C0.c[b], lo0, ax[b]);
      ay[b] = fdot2(C0.c[b], hi0, ay[b]);
    }
  }

  union { _Float16 e[8]; uint4 q; } p0, p1;
  #pragma unroll
  for (int b = 0; b < NB; b++) { p0.e[b] = (_Float16)ax[b]; p1.e[b] = (_Float16)ay[b]; }
  uint4* dstp = (uint4*)&agg[(size_t)v * 1024 + lane * 16];
  dstp[0] = p0.q;
  dstp[1] = p1.q;
}

// ---------------------------------------------------------------------------
// MFMA GEMM: TN=64, 512 threads / 8 waves, BK=128 (9 K-tiles: 8 agg + 1 hf).
// LDS tile: [16 kslot][64 node][8 halves] = 16KB, double-buffered.
// Wave wv stages kslots wv and wv+8 (2 gld_lds per tile, lane = node).
// COMPUTE: 4 sub-steps x {1 A-load (L2-hot WcA) + 4 ds_read + 4 MFMA}.
// ---------------------------------------------------------------------------
template <int LAYER>
__global__ __launch_bounds__(512) void k_mm(
    const _Float16* __restrict__ agg,   // [N][1024]
    const _Float16* __restrict__ hf,    // [N][128]
    const _Float16* __restrict__ WcA,   // [36][128][32]
    const float* __restrict__ bias,
    float* __restrict__ outf, _Float16* __restrict__ outh, int N)
{
  __shared__ _Float16 sB[2][8192];      // 2 x 16KB

  const int n0   = blockIdx.x * 64;
  const int wv   = threadIdx.x >> 6;    // 0..7
  const int lane = threadIdx.x & 63;
  const int l15  = lane & 15, l4 = lane >> 4;

  int nodeL = n0 + lane; if (nodeL >= N) nodeL = N - 1;   // stage-source clamp

  f32x4 acc[4];
  #pragma unroll
  for (int b = 0; b < 4; b++) acc[b] = (f32x4)0.f;

  const int fbase = wv * 16 + l15;
  const int koff  = l4 * 8;

  auto STAGE = [&](int buf, int t) {    // t in 0..8
    const _Float16* g;
    if (t < 8) g = &agg[(size_t)nodeL * 1024 + t * 128 + wv * 8];
    else       g = &hf [(size_t)nodeL * DD   + wv * 8];
    gld_lds16(g,      &sB[buf][ wv      * 512]);   // kslot wv
    gld_lds16(g + 64, &sB[buf][(wv + 8) * 512]);   // kslot wv+8
  };

  auto COMPUTE = [&](int buf, int t) {
    #pragma unroll
    for (int s = 0; s < 4; s++) {
      const int ks = 4 * t + s;         // 0..35
      half8v af = *(const half8v*)&WcA[((size_t)ks * DD + fbase) * 32 + koff];
      half8v bfr[4];
      #pragma unroll
      for (int nf = 0; nf < 4; nf++)
        bfr[nf] = *(const half8v*)&sB[buf][(s * 4 + l4) * 512 + (nf * 16 + l15) * 8];
      #pragma unroll
      for (int nf = 0; nf < 4; nf++)
        acc[nf] = __builtin_amdgcn_mfma_f32_16x16x32_f16(af, bfr[nf], acc[nf], 0, 0, 0);
    }
  };

  STAGE(0, 0);
  __syncthreads();
  int cur = 0;
  for (int t = 0; t < 8; t++) {
    STAGE(cur ^ 1, t + 1);
    COMPUTE(cur, t);
    __syncthreads();
    cur ^= 1;
  }
  COMPUTE(cur, 8);

  // C layout: col(=node) = lane&15, row(=feat) = l4*4 + r
  #pragma unroll
  for (int nf = 0; nf < 4; nf++) {
    int n = n0 + nf * 16 + l15;
    if (n >= N) continue;
    int feat = wv * 16 + l4 * 4;
    if (LAYER == 1) {
      union { _Float16 e[4]; uint2 q; } p;
      #pragma unroll
      for (int r = 0; r < 4; r++)
        p.e[r] = (_Float16)fmaxf(acc[nf][r] + bias[feat + r], 0.f);
      *(uint2*)&outh[(size_t)n * DD + feat] = p.q;
    } else {
      float4 o;
      o.x = acc[nf][0] + bias[feat + 0];
      o.y = acc[nf][1] + bias[feat + 1];
      o.z = acc[nf][2] + bias[feat + 2];
      o.w = acc[nf][3] + bias[feat + 3];
      *(float4*)&outf[(size_t)n * DD + feat] = o;
    }
  }
}

extern "C" void kernel_launch(void* const* d_in, const int* in_sizes, int n_in,
                              void* d_out, int out_size, void* d_ws, size_t ws_size,
                              hipStream_t stream)
{
  const int*   h_ids     = (const int*)d_in[0];
  const int*   src       = (const int*)d_in[1];
  const int*   dst       = (const int*)d_in[2];
  const int*   etype     = (const int*)d_in[3];
  const float* norm      = (const float*)d_in[4];
  const float* embedding = (const float*)d_in[5];
  const float* w_comp1   = (const float*)d_in[6];
  const float* bases1    = (const float*)d_in[7];
  const float* loop_w1   = (const float*)d_in[8];
  const float* bias1     = (const float*)d_in[9];
  const float* w_comp2   = (const float*)d_in[10];
  const float* bases2    = (const float*)d_in[11];
  const float* loop_w2   = (const float*)d_in[12];
  const float* bias2     = (const float*)d_in[13];

  const int N = in_sizes[0];
  const int E = in_sizes[1];
  const int S = (E + N) & ~1;           // padded-slot capacity (even)
  const int NPAIR = S >> 1;
  const int NBLK = (N + 255) / 256;     // <= 256 (N <= 65536)

  // ---- workspace carve-up (256B aligned) ----
  char* base = (char*)d_ws;
  size_t off = 0;
  auto alloc = [&](size_t bytes) -> char* {
    char* p = base + off;
    off += (bytes + 255) & ~(size_t)255;
    return p;
  };
  _Float16* agg  = (_Float16*)alloc((size_t)N * 1024 * 2);   // 102.4 MB
  _Float16* hfp  = (_Float16*)alloc((size_t)N * DD * 2);     // 12.8 MB
  _Float16* h1h  = (_Float16*)alloc((size_t)N * DD * 2);     // 12.8 MB
  _Float16* WcA  = (_Float16*)alloc((size_t)2 * 36 * DD * 32 * 2);
  int*      cnt    = (int*)   alloc((size_t)N * 4);
  int4*     en4    = (int4*)  alloc((size_t)S * 16);
  int*      rowst  = (int*)   alloc((size_t)N * 4);
  int*      bsum   = (int*)   alloc(256 * 4);
  int*      boff   = (int*)   alloc(256 * 4);
  int*      tot    = (int*)   alloc(256);
  int*      slotin = (int*)   alloc((size_t)E * 4);
  int*      psrc   = (int*)   alloc((size_t)S * 4);
  _Float16* c1     = (_Float16*)alloc((size_t)S * 8 * 2);    // ~10.4 MB
  _Float16* c2     = (_Float16*)alloc((size_t)S * 8 * 2);    // ~10.4 MB
  float*    out    = (float*)d_out;

  // ---- build padded CSR by dst (reused by both layers) ----
  k_zero <<<(N + 255) / 256, 256, 0, stream>>>(cnt, N);
  k_hist <<<(E + 255) / 256, 256, 0, stream>>>(dst, cnt, slotin, E);
  k_bsum <<<NBLK, 256, 0, stream>>>(cnt, bsum, N);
  k_scanb<<<1, 256, 0, stream>>>(bsum, boff, tot, NBLK);
  k_scan3<<<NBLK, 256, 0, stream>>>(cnt, boff, rowst, en4, N);
  k_place<<<(E + 255) / 256, 256, 0, stream>>>(dst, src, etype, norm,
                                               rowst, slotin, en4, E);
  k_payload_pair<<<(NPAIR + 255) / 256, 256, 0, stream>>>(
      en4, tot, w_comp1, w_comp2, psrc, c1, c2, NPAIR);

  // ---- weights -> fp16 A-coalesced layout ----
  k_prep_w<<<(2 * 36 * DD * 32 + 255) / 256, 256, 0, stream>>>(bases1, loop_w1, bases2, loop_w2, WcA);

  dim3 gmm((N + 63) / 64);
  int gagg = (N + 3) / 4;

  // ---- layer 1 ----
  k_cast<<<(N * (DD / 8) + 255) / 256, 256, 0, stream>>>(embedding, h_ids, hfp, N);
  k_agg<<<gagg, 256, 0, stream>>>(rowst, cnt, psrc, c1, hfp, agg, N);
  k_mm<1><<<gmm, 512, 0, stream>>>(agg, hfp, WcA, bias1, nullptr, h1h, N);

  // ---- layer 2 ----
  k_agg<<<gagg, 256, 0, stream>>>(rowst, cnt, psrc, c2, h1h, agg, N);
  k_mm<2><<<gmm, 512, 0, stream>>>(agg, h1h, WcA + (size_t)36 * DD * 32, bias2, out, nullptr, N);
}